// Round 4
// baseline (3044.587 us; speedup 1.0000x reference)
//
#include <hip/hip_runtime.h>
#include <hip/hip_bf16.h>

// Problem constants
#define B_   8
#define L_   1024
#define C_   512
#define DI_  1024
#define K_   4
#define N_   16
#define R_   32
#define HW_  32
#define M_   (B_ * L_)   // 8192 rows
#define NC_  8           // scan chunks
#define CL_  128         // chunk length = L_/NC_

typedef __attribute__((ext_vector_type(8))) short short8;   // 8 bf16 (4 VGPRs)
typedef __attribute__((ext_vector_type(4))) float f32x4;

__device__ __forceinline__ void gload_lds16(const void* g, void* l) {
  __builtin_amdgcn_global_load_lds(
      (const __attribute__((address_space(1))) void*)g,
      (__attribute__((address_space(3))) void*)l, 16, 0, 0);
}

// Map scan position p -> spatial index l (same map for gather of u and scatter of y)
__device__ __forceinline__ int sp_map(int k, int p) {
  if (k == 0) return p;
  if (k == 1) return ((p & 31) << 5) | (p >> 5);      // (p%H)*W + p/H
  if (k == 2) return 1023 - p;
  int q = 1023 - p;
  return ((q & 31) << 5) | (q >> 5);
}

__device__ __forceinline__ float softplus_fast(float x) {
  return (x > 20.f) ? x : __logf(1.f + __expf(x));
}

__device__ __forceinline__ float block_sum_256(float v, float* sm) {
  #pragma unroll
  for (int o = 32; o > 0; o >>= 1) v += __shfl_down(v, o);
  int wid = threadIdx.x >> 6;
  if ((threadIdx.x & 63) == 0) sm[wid] = v;
  __syncthreads();
  float r = sm[0] + sm[1] + sm[2] + sm[3];
  __syncthreads();
  return r;
}

// ---------------- weight cast f32 -> bf16 (vectorized) ----------------
__global__ __launch_bounds__(256) void cast_bf16_kernel(const float* __restrict__ in,
    __hip_bfloat16* __restrict__ out, int n4) {
  int i = blockIdx.x * 256 + threadIdx.x;
  if (i >= n4) return;
  float4 v = ((const float4*)in)[i];
  union { __hip_bfloat16 h[4]; short4 s; } pk;
  pk.h[0] = __float2bfloat16(v.x); pk.h[1] = __float2bfloat16(v.y);
  pk.h[2] = __float2bfloat16(v.z); pk.h[3] = __float2bfloat16(v.w);
  ((short4*)out)[i] = pk.s;
}

// ---------------- 1) LayerNorm over C=512 (emits bf16) ----------------
__global__ __launch_bounds__(256) void ln_kernel(const float* __restrict__ x,
    const float* __restrict__ w, const float* __restrict__ b,
    __hip_bfloat16* __restrict__ xn) {
  int row = blockIdx.x;
  const float* xr = x + (size_t)row * C_;
  int t = threadIdx.x;
  float v0 = xr[t], v1 = xr[t + 256];
  __shared__ float sm[4];
  float s = block_sum_256(v0 + v1, sm);
  float mu = s * (1.0f / C_);
  float d0 = v0 - mu, d1 = v1 - mu;
  float q = block_sum_256(d0 * d0 + d1 * d1, sm);
  float rs = rsqrtf(q * (1.0f / C_) + 1e-5f);
  __hip_bfloat16* xo = xn + (size_t)row * C_;
  xo[t]       = __float2bfloat16(d0 * rs * w[t] + b[t]);
  xo[t + 256] = __float2bfloat16(d1 * rs * w[t + 256] + b[t + 256]);
}

// ---------------- bf16 MFMA GEMM: C[m,n] = sum_k A[m,k]*Bw[n,k] ----------------
template <int MODE>
__global__ __launch_bounds__(256) void gemm_bf16(
    const __hip_bfloat16* __restrict__ A, const __hip_bfloat16* __restrict__ Bw,
    const int M, const int N, const int K,
    float* __restrict__ O0, float* __restrict__ O1, const float* __restrict__ resid) {
  __shared__ __align__(16) __hip_bfloat16 Asm[128][32];  // 8 KB, linear (global_load_lds dest)
  __shared__ __align__(16) __hip_bfloat16 Bsm[128][32];  // 8 KB
  const int bm = blockIdx.y * 128, bn = blockIdx.x * 128;
  const int tid = threadIdx.x, lane = tid & 63, wid = tid >> 6;
  const int wr = (wid >> 1) * 64, wc = (wid & 1) * 64;   // wave's 64x64 output origin
  const int fr = lane & 15, fq = lane >> 4;

  f32x4 acc[4][4] = {};

  const int r0 = tid >> 2, c0 = (tid & 3) * 8;
  const int r1 = (tid + 256) >> 2;
  const __hip_bfloat16* Ag0 = A + (size_t)(bm + r0) * K + c0;
  const __hip_bfloat16* Ag1 = A + (size_t)(bm + r1) * K + c0;
  const __hip_bfloat16* Bg0 = Bw + (size_t)(bn + r0) * K + c0;
  const __hip_bfloat16* Bg1 = Bw + (size_t)(bn + r1) * K + c0;
  char* ldsA0 = (char*)Asm + wid * 1024;          // wave-uniform base; HW adds lane*16
  char* ldsA1 = (char*)Asm + 4096 + wid * 1024;
  char* ldsB0 = (char*)Bsm + wid * 1024;
  char* ldsB1 = (char*)Bsm + 4096 + wid * 1024;

  for (int k0 = 0; k0 < K; k0 += 32) {
    __syncthreads();
    gload_lds16(Ag0 + k0, ldsA0);
    gload_lds16(Ag1 + k0, ldsA1);
    gload_lds16(Bg0 + k0, ldsB0);
    gload_lds16(Bg1 + k0, ldsB1);
    __syncthreads();

    short8 af[4], bf[4];
    #pragma unroll
    for (int i = 0; i < 4; ++i) {
      af[i] = *(const short8*)((const char*)Asm + (wr + i * 16 + fr) * 64 + fq * 16);
      bf[i] = *(const short8*)((const char*)Bsm + (wc + i * 16 + fr) * 64 + fq * 16);
    }
    #pragma unroll
    for (int i = 0; i < 4; ++i)
      #pragma unroll
      for (int j = 0; j < 4; ++j)
        acc[i][j] = __builtin_amdgcn_mfma_f32_16x16x32_bf16(af[i], bf[j], acc[i][j], 0, 0, 0);
  }

  const int half = N >> 1;
  #pragma unroll
  for (int i = 0; i < 4; ++i) {
    const int mrow = bm + wr + i * 16 + fq * 4;
    #pragma unroll
    for (int j = 0; j < 4; ++j) {
      const int n = bn + wc + j * 16 + fr;
      #pragma unroll
      for (int r = 0; r < 4; ++r) {
        const int m = mrow + r;
        const float v = acc[i][j][r];
        if (MODE == 0) {
          if (n < half) O0[(size_t)m * half + n] = v;
          else          O1[(size_t)m * half + (n - half)] = v;
        } else {
          O0[(size_t)m * N + n] = v + resid[(size_t)m * N + n];
        }
      }
    }
  }
}

// ---------------- 3) depthwise 3x3 conv + bias + SiLU ----------------
__global__ __launch_bounds__(256) void conv_silu_kernel(const float* __restrict__ xpart,
    const float* __restrict__ cw, const float* __restrict__ cb, float* __restrict__ xc) {
  int bl = blockIdx.x;
  int b = bl >> 10, l = bl & 1023;
  int h = l >> 5, w = l & 31;
  for (int d = threadIdx.x; d < DI_; d += 256) {
    float acc = cb[d];
    #pragma unroll
    for (int dy = -1; dy <= 1; ++dy) {
      int hh = h + dy;
      if (hh < 0 || hh >= HW_) continue;
      #pragma unroll
      for (int dx = -1; dx <= 1; ++dx) {
        int ww = w + dx;
        if (ww < 0 || ww >= HW_) continue;
        acc += cw[d * 9 + (dy + 1) * 3 + (dx + 1)] *
               xpart[((size_t)(b << 10) + (hh << 5) + ww) * DI_ + d];
      }
    }
    xc[(size_t)bl * DI_ + d] = acc / (1.0f + __expf(-acc));
  }
}

// ---------------- 4) x_dbl[b,k,p,c] = sum_d xc[b, sp(k,p), d] * xproj[k,c,d] ----------------
__global__ __launch_bounds__(256) void xdbl_kernel(const float* __restrict__ xc,
    const float* __restrict__ xproj, float* __restrict__ xdbl) {
  int blk = blockIdx.x;
  int pt = blk & 63;
  int k  = (blk >> 6) & 3;
  int b  = blk >> 8;
  int p0 = pt * 16;
  __shared__ float Xs[16][64];
  __shared__ float Ws[64][65];
  int lane = threadIdx.x & 63;
  int wv4 = (threadIdx.x >> 6) * 4;
  float acc[4] = {0.f, 0.f, 0.f, 0.f};
  for (int d0 = 0; d0 < DI_; d0 += 64) {
    __syncthreads();
    #pragma unroll
    for (int i = 0; i < 4; ++i) {
      int e = threadIdx.x + i * 256;
      int pi = e >> 6, col = e & 63;
      Xs[pi][col] = xc[((size_t)(b * 1024 + sp_map(k, p0 + pi))) * DI_ + d0 + col];
    }
    #pragma unroll
    for (int i = 0; i < 16; ++i) {
      int e = threadIdx.x + i * 256;
      int dd = e & 63, cc = e >> 6;
      Ws[dd][cc] = xproj[((size_t)(k * 64 + cc)) * DI_ + d0 + dd];
    }
    __syncthreads();
    #pragma unroll
    for (int dc = 0; dc < 64; ++dc) {
      float wval = Ws[dc][lane];
      #pragma unroll
      for (int q = 0; q < 4; ++q) acc[q] += wval * Xs[wv4 + q][dc];
    }
  }
  #pragma unroll
  for (int q = 0; q < 4; ++q) {
    int p = p0 + wv4 + q;
    xdbl[(((size_t)(b * 4 + k)) * 1024 + p) * 64 + lane] = acc[q];
  }
}

// ---------------- 5a) scan pass A: per-chunk local scan + chunk summary ----------------
// grid: (((b*4+k)*NC_+c)*4+dgrp) blocks x 256 thr. thread -> d = dgrp*256+tid.
// st[g*NC_+c][slot]: slot n*64+lane = P[n]; 1024 + n*64+lane = h_end (g=(b*4+k)*16+(d>>6))
__global__ __launch_bounds__(256, 4) void scan_passA(const float* __restrict__ xc,
    const float* __restrict__ xdbl, const float* __restrict__ dtw,
    const float* __restrict__ dtb, const float* __restrict__ Alogs,
    float* __restrict__ st) {
  const int blk = blockIdx.x;
  const int dgrp = blk & 3;
  const int c    = (blk >> 2) & (NC_ - 1);
  const int k    = (blk >> 5) & 3;
  const int b    = blk >> 7;
  const int tid = threadIdx.x;
  const int d = dgrp * 256 + tid;
  const int kd = k * DI_ + d;

  float dtwr[32];
  #pragma unroll
  for (int r = 0; r < 8; ++r)
    *(float4*)&dtwr[r * 4] = ((const float4*)(dtw + (size_t)kd * 32))[r];
  float A[16], h[16];
  #pragma unroll
  for (int n = 0; n < 16; ++n) {
    A[n] = -__expf(Alogs[(size_t)kd * 16 + n]);
    h[n] = 0.f;
  }
  const float bias = dtb[kd];
  float S = 0.f;

  __shared__ __align__(16) float Ls[16 * 64];
  const float* xrow = xdbl + ((size_t)((b * 4 + k) * 1024 + c * CL_)) * 64;
  const float* xcb  = xc + ((size_t)b << 20) + d;   // + sp*1024 per step
  const int p0g = c * CL_;

  for (int pt = 0; pt < CL_; pt += 16) {
    __syncthreads();
    ((float4*)Ls)[tid] = ((const float4*)(xrow + pt * 64))[tid];
    __syncthreads();
    #pragma unroll
    for (int pp = 0; pp < 16; ++pp) {
      const float* row = Ls + pp * 64;
      int sp = sp_map(k, p0g + pt + pp);
      float u = xcb[sp << 10];
      float dtr = bias;
      #pragma unroll
      for (int r4 = 0; r4 < 8; ++r4) {
        float4 rv = ((const float4*)row)[r4];
        dtr += dtwr[r4 * 4 + 0] * rv.x + dtwr[r4 * 4 + 1] * rv.y +
               dtwr[r4 * 4 + 2] * rv.z + dtwr[r4 * 4 + 3] * rv.w;
      }
      float dt = softplus_fast(dtr);
      S += dt;
      float dtu = dt * u;
      #pragma unroll
      for (int n4 = 0; n4 < 4; ++n4) {
        float4 bv = ((const float4*)(row + 32))[n4];
        h[n4 * 4 + 0] = h[n4 * 4 + 0] * __expf(dt * A[n4 * 4 + 0]) + dtu * bv.x;
        h[n4 * 4 + 1] = h[n4 * 4 + 1] * __expf(dt * A[n4 * 4 + 1]) + dtu * bv.y;
        h[n4 * 4 + 2] = h[n4 * 4 + 2] * __expf(dt * A[n4 * 4 + 2]) + dtu * bv.z;
        h[n4 * 4 + 3] = h[n4 * 4 + 3] * __expf(dt * A[n4 * 4 + 3]) + dtu * bv.w;
      }
    }
  }
  const int g = (b * 4 + k) * 16 + (d >> 6);
  const int lane = d & 63;
  size_t base = ((size_t)g * NC_ + c) * 2048;
  #pragma unroll
  for (int n = 0; n < 16; ++n) {
    st[base + n * 64 + lane]        = __expf(A[n] * S);
    st[base + 1024 + n * 64 + lane] = h[n];
  }
}

// ---------------- 5b) combine chunk states; overwrite h-slot with H_in(c) ----------------
__global__ __launch_bounds__(256) void scan_mid(float* __restrict__ st) {
  int idx = blockIdx.x * 256 + threadIdx.x;   // 32768 threads: (g, lane)
  int lane = idx & 63;
  int g = idx >> 6;
  float H[16];
  #pragma unroll
  for (int n = 0; n < 16; ++n) H[n] = 0.f;
  for (int c = 0; c < NC_; ++c) {
    size_t base = ((size_t)g * NC_ + c) * 2048;
    #pragma unroll
    for (int n = 0; n < 16; ++n) {
      float P  = st[base + n * 64 + lane];
      float he = st[base + 1024 + n * 64 + lane];
      st[base + 1024 + n * 64 + lane] = H[n];           // H_in for chunk c
      H[n] = he + P * H[n];
    }
  }
}

// ---------------- 5c) scan pass B: rescan chunk from H_in, emit y ----------------
__global__ __launch_bounds__(256, 4) void scan_passB(const float* __restrict__ xc,
    const float* __restrict__ xdbl, const float* __restrict__ dtw,
    const float* __restrict__ dtb, const float* __restrict__ Alogs,
    const float* __restrict__ Ds, const float* __restrict__ st,
    __hip_bfloat16* __restrict__ ys) {
  const int blk = blockIdx.x;
  const int dgrp = blk & 3;
  const int c    = (blk >> 2) & (NC_ - 1);
  const int k    = (blk >> 5) & 3;
  const int b    = blk >> 7;
  const int tid = threadIdx.x;
  const int d = dgrp * 256 + tid;
  const int kd = k * DI_ + d;

  float dtwr[32];
  #pragma unroll
  for (int r = 0; r < 8; ++r)
    *(float4*)&dtwr[r * 4] = ((const float4*)(dtw + (size_t)kd * 32))[r];
  const int g = (b * 4 + k) * 16 + (d >> 6);
  const int lane = d & 63;
  const size_t sbase = ((size_t)g * NC_ + c) * 2048;
  float A[16], h[16];
  #pragma unroll
  for (int n = 0; n < 16; ++n) {
    A[n] = -__expf(Alogs[(size_t)kd * 16 + n]);
    h[n] = st[sbase + 1024 + n * 64 + lane];
  }
  const float bias = dtb[kd];
  const float Dv = Ds[kd];

  __shared__ __align__(16) float Ls[16 * 64];
  const float* xrow = xdbl + ((size_t)((b * 4 + k) * 1024 + c * CL_)) * 64;
  const float* xcb  = xc + ((size_t)b << 20) + d;
  __hip_bfloat16* ysb = ys + ((size_t)(b << 12) + k) * 1024 + d;  // + sp*4096 per step
  const int p0g = c * CL_;

  for (int pt = 0; pt < CL_; pt += 16) {
    __syncthreads();
    ((float4*)Ls)[tid] = ((const float4*)(xrow + pt * 64))[tid];
    __syncthreads();
    #pragma unroll
    for (int pp = 0; pp < 16; ++pp) {
      const float* row = Ls + pp * 64;
      int sp = sp_map(k, p0g + pt + pp);
      float u = xcb[sp << 10];
      float dtr = bias;
      #pragma unroll
      for (int r4 = 0; r4 < 8; ++r4) {
        float4 rv = ((const float4*)row)[r4];
        dtr += dtwr[r4 * 4 + 0] * rv.x + dtwr[r4 * 4 + 1] * rv.y +
               dtwr[r4 * 4 + 2] * rv.z + dtwr[r4 * 4 + 3] * rv.w;
      }
      float dt = softplus_fast(dtr);
      float dtu = dt * u;
      float y = 0.f;
      #pragma unroll
      for (int n4 = 0; n4 < 4; ++n4) {
        float4 bv = ((const float4*)(row + 32))[n4];
        float4 cv = ((const float4*)(row + 48))[n4];
        h[n4 * 4 + 0] = h[n4 * 4 + 0] * __expf(dt * A[n4 * 4 + 0]) + dtu * bv.x;
        h[n4 * 4 + 1] = h[n4 * 4 + 1] * __expf(dt * A[n4 * 4 + 1]) + dtu * bv.y;
        h[n4 * 4 + 2] = h[n4 * 4 + 2] * __expf(dt * A[n4 * 4 + 2]) + dtu * bv.z;
        h[n4 * 4 + 3] = h[n4 * 4 + 3] * __expf(dt * A[n4 * 4 + 3]) + dtu * bv.w;
        y += h[n4 * 4 + 0] * cv.x + h[n4 * 4 + 1] * cv.y +
             h[n4 * 4 + 2] * cv.z + h[n4 * 4 + 3] * cv.w;
      }
      y += Dv * u;
      ysb[(size_t)sp << 12] = __float2bfloat16(y);
    }
  }
}

// ---------------- 6) merge(sum k) + LayerNorm(DI) + SiLU(z) gate (emits bf16) ----------------
__global__ __launch_bounds__(256) void merge_kernel(const __hip_bfloat16* __restrict__ ys,
    const float* __restrict__ z, const float* __restrict__ ow, const float* __restrict__ ob,
    __hip_bfloat16* __restrict__ ym) {
  int bl = blockIdx.x;
  int t = threadIdx.x;
  float v[4];
  float s = 0.f;
  #pragma unroll
  for (int i = 0; i < 4; ++i) {
    int d = t + i * 256;
    float acc = 0.f;
    #pragma unroll
    for (int kk = 0; kk < 4; ++kk)
      acc += __bfloat162float(ys[(((size_t)bl) * 4 + kk) * DI_ + d]);
    v[i] = acc;
    s += acc;
  }
  __shared__ float sm[4];
  float tot = block_sum_256(s, sm);
  float mu = tot * (1.0f / DI_);
  float q = 0.f;
  #pragma unroll
  for (int i = 0; i < 4; ++i) { float dv = v[i] - mu; q += dv * dv; }
  float qs = block_sum_256(q, sm);
  float rs = rsqrtf(qs * (1.0f / DI_) + 1e-5f);
  #pragma unroll
  for (int i = 0; i < 4; ++i) {
    int d = t + i * 256;
    float ln = (v[i] - mu) * rs * ow[d] + ob[d];
    float zv = z[(size_t)bl * DI_ + d];
    ym[(size_t)bl * DI_ + d] = __float2bfloat16(ln * (zv / (1.0f + __expf(-zv))));
  }
}

// ---------------- launcher ----------------
extern "C" void kernel_launch(void* const* d_in, const int* in_sizes, int n_in,
                              void* d_out, int out_size, void* d_ws, size_t ws_size,
                              hipStream_t stream) {
  const float* x         = (const float*)d_in[0];
  const float* norm_w    = (const float*)d_in[1];
  const float* norm_b    = (const float*)d_in[2];
  const float* in_proj_w = (const float*)d_in[3];
  const float* conv_w    = (const float*)d_in[4];
  const float* conv_b    = (const float*)d_in[5];
  const float* x_proj_w  = (const float*)d_in[6];
  const float* dt_projs_w= (const float*)d_in[7];
  const float* dt_projs_b= (const float*)d_in[8];
  const float* A_logs    = (const float*)d_in[9];
  const float* Ds        = (const float*)d_in[10];
  const float* out_norm_w= (const float*)d_in[11];
  const float* out_norm_b= (const float*)d_in[12];
  const float* out_proj_w= (const float*)d_in[13];
  float* out = (float*)d_out;

  // workspace layout (liveness-packed, total 187,695,104 B)
  char* ws = (char*)d_ws;
  float* z              = (float*)(ws);                         // 33.55 MB [GEMM1..merge]
  float* xc             = (float*)(ws + 33554432ULL);           // 33.55 MB [conv..passB]
  float* xpart          = (float*)(ws + 67108864ULL);           // 33.55 MB [GEMM1..conv]
  float* st             = xpart;                                //          [passA..passB]
  __hip_bfloat16* ymb   = (__hip_bfloat16*)xpart;               // 16.8 MB  [merge..GEMM2]
  float* xdbl           = (float*)(ws + 100663296ULL);          //  8.39 MB [xdbl..passB]
  __hip_bfloat16* ys    = (__hip_bfloat16*)(ws + 109051904ULL); // 67.11 MB [passB..merge]
  __hip_bfloat16* xnb   = (__hip_bfloat16*)(ws + 176160768ULL); //  8.39 MB [ln..GEMM1]
  __hip_bfloat16* w1b   = (__hip_bfloat16*)(ws + 184549376ULL); //  2.10 MB [cast..GEMM1]
  __hip_bfloat16* w2b   = (__hip_bfloat16*)(ws + 186646528ULL); //  1.05 MB [cast..GEMM2]

  // 0) weight casts
  cast_bf16_kernel<<<1024, 256, 0, stream>>>(in_proj_w, w1b, (2048 * 512) / 4);
  cast_bf16_kernel<<<512, 256, 0, stream>>>(out_proj_w, w2b, (512 * 1024) / 4);
  // 1) LayerNorm (bf16 out)
  ln_kernel<<<M_, 256, 0, stream>>>(x, norm_w, norm_b, xnb);
  // 2) xz = xn @ in_proj_w.T  (MFMA) -> split xpart | z (f32)
  gemm_bf16<0><<<dim3(2048 / 128, M_ / 128), 256, 0, stream>>>(
      xnb, w1b, M_, 2048, C_, xpart, z, nullptr);
  // 3) depthwise conv + SiLU
  conv_silu_kernel<<<M_, 256, 0, stream>>>(xpart, conv_w, conv_b, xc);
  // 4) x_dbl projections
  xdbl_kernel<<<B_ * K_ * 64, 256, 0, stream>>>(xc, x_proj_w, xdbl);
  // 5) chunked parallel selective scan (256-thread blocks, 16-row staging)
  scan_passA<<<B_ * K_ * NC_ * 4, 256, 0, stream>>>(
      xc, xdbl, dt_projs_w, dt_projs_b, A_logs, st);
  scan_mid<<<(B_ * K_ * DI_) / 256, 256, 0, stream>>>(st);
  scan_passB<<<B_ * K_ * NC_ * 4, 256, 0, stream>>>(
      xc, xdbl, dt_projs_w, dt_projs_b, A_logs, Ds, st, ys);
  // 6) merge + out-LN + SiLU(z) gate (bf16 out)
  merge_kernel<<<M_, 256, 0, stream>>>(ys, z, out_norm_w, out_norm_b, ymb);
  // 7) out = ym @ out_proj_w.T + resid (MFMA)
  gemm_bf16<1><<<dim3(C_ / 128, M_ / 128), 256, 0, stream>>>(
      ymb, w2b, M_, C_, DI_, out, nullptr, x);
}

// Round 5
// 2946.278 us; speedup vs baseline: 1.0334x; 1.0334x over previous
//
#include <hip/hip_runtime.h>
#include <hip/hip_bf16.h>

// Problem constants
#define B_   8
#define L_   1024
#define C_   512
#define DI_  1024
#define K_   4
#define N_   16
#define R_   32
#define HW_  32
#define M_   (B_ * L_)   // 8192 rows
#define NC_  8           // scan chunks
#define CL_  128         // chunk length = L_/NC_

typedef __attribute__((ext_vector_type(8))) short short8;   // 8 bf16 (4 VGPRs)
typedef __attribute__((ext_vector_type(4))) float f32x4;

__device__ __forceinline__ void gload_lds16(const void* g, void* l) {
  __builtin_amdgcn_global_load_lds(
      (const __attribute__((address_space(1))) void*)g,
      (__attribute__((address_space(3))) void*)l, 16, 0, 0);
}

// Map scan position p -> spatial index l (same map for gather of u and scatter of y)
__device__ __forceinline__ int sp_map(int k, int p) {
  if (k == 0) return p;
  if (k == 1) return ((p & 31) << 5) | (p >> 5);      // (p%H)*W + p/H
  if (k == 2) return 1023 - p;
  int q = 1023 - p;
  return ((q & 31) << 5) | (q >> 5);
}

__device__ __forceinline__ float softplus_fast(float x) {
  return (x > 20.f) ? x : __logf(1.f + __expf(x));
}

__device__ __forceinline__ float block_sum_256(float v, float* sm) {
  #pragma unroll
  for (int o = 32; o > 0; o >>= 1) v += __shfl_down(v, o);
  int wid = threadIdx.x >> 6;
  if ((threadIdx.x & 63) == 0) sm[wid] = v;
  __syncthreads();
  float r = sm[0] + sm[1] + sm[2] + sm[3];
  __syncthreads();
  return r;
}

// ---------------- weight cast f32 -> bf16 (vectorized) ----------------
__global__ __launch_bounds__(256) void cast_bf16_kernel(const float* __restrict__ in,
    __hip_bfloat16* __restrict__ out, int n4) {
  int i = blockIdx.x * 256 + threadIdx.x;
  if (i >= n4) return;
  float4 v = ((const float4*)in)[i];
  union { __hip_bfloat16 h[4]; short4 s; } pk;
  pk.h[0] = __float2bfloat16(v.x); pk.h[1] = __float2bfloat16(v.y);
  pk.h[2] = __float2bfloat16(v.z); pk.h[3] = __float2bfloat16(v.w);
  ((short4*)out)[i] = pk.s;
}

// ---------------- 1) LayerNorm over C=512 (emits bf16) ----------------
__global__ __launch_bounds__(256) void ln_kernel(const float* __restrict__ x,
    const float* __restrict__ w, const float* __restrict__ b,
    __hip_bfloat16* __restrict__ xn) {
  int row = blockIdx.x;
  const float* xr = x + (size_t)row * C_;
  int t = threadIdx.x;
  float v0 = xr[t], v1 = xr[t + 256];
  __shared__ float sm[4];
  float s = block_sum_256(v0 + v1, sm);
  float mu = s * (1.0f / C_);
  float d0 = v0 - mu, d1 = v1 - mu;
  float q = block_sum_256(d0 * d0 + d1 * d1, sm);
  float rs = rsqrtf(q * (1.0f / C_) + 1e-5f);
  __hip_bfloat16* xo = xn + (size_t)row * C_;
  xo[t]       = __float2bfloat16(d0 * rs * w[t] + b[t]);
  xo[t + 256] = __float2bfloat16(d1 * rs * w[t + 256] + b[t + 256]);
}

// ---------------- bf16 MFMA GEMM: C[m,n] = sum_k A[m,k]*Bw[n,k] ----------------
template <int MODE>
__global__ __launch_bounds__(256) void gemm_bf16(
    const __hip_bfloat16* __restrict__ A, const __hip_bfloat16* __restrict__ Bw,
    const int M, const int N, const int K,
    float* __restrict__ O0, float* __restrict__ O1, const float* __restrict__ resid) {
  __shared__ __align__(16) __hip_bfloat16 Asm[128][32];  // 8 KB, linear (global_load_lds dest)
  __shared__ __align__(16) __hip_bfloat16 Bsm[128][32];  // 8 KB
  const int bm = blockIdx.y * 128, bn = blockIdx.x * 128;
  const int tid = threadIdx.x, lane = tid & 63, wid = tid >> 6;
  const int wr = (wid >> 1) * 64, wc = (wid & 1) * 64;   // wave's 64x64 output origin
  const int fr = lane & 15, fq = lane >> 4;

  f32x4 acc[4][4] = {};

  const int r0 = tid >> 2, c0 = (tid & 3) * 8;
  const int r1 = (tid + 256) >> 2;
  const __hip_bfloat16* Ag0 = A + (size_t)(bm + r0) * K + c0;
  const __hip_bfloat16* Ag1 = A + (size_t)(bm + r1) * K + c0;
  const __hip_bfloat16* Bg0 = Bw + (size_t)(bn + r0) * K + c0;
  const __hip_bfloat16* Bg1 = Bw + (size_t)(bn + r1) * K + c0;
  char* ldsA0 = (char*)Asm + wid * 1024;          // wave-uniform base; HW adds lane*16
  char* ldsA1 = (char*)Asm + 4096 + wid * 1024;
  char* ldsB0 = (char*)Bsm + wid * 1024;
  char* ldsB1 = (char*)Bsm + 4096 + wid * 1024;

  for (int k0 = 0; k0 < K; k0 += 32) {
    __syncthreads();
    gload_lds16(Ag0 + k0, ldsA0);
    gload_lds16(Ag1 + k0, ldsA1);
    gload_lds16(Bg0 + k0, ldsB0);
    gload_lds16(Bg1 + k0, ldsB1);
    __syncthreads();

    short8 af[4], bf[4];
    #pragma unroll
    for (int i = 0; i < 4; ++i) {
      af[i] = *(const short8*)((const char*)Asm + (wr + i * 16 + fr) * 64 + fq * 16);
      bf[i] = *(const short8*)((const char*)Bsm + (wc + i * 16 + fr) * 64 + fq * 16);
    }
    #pragma unroll
    for (int i = 0; i < 4; ++i)
      #pragma unroll
      for (int j = 0; j < 4; ++j)
        acc[i][j] = __builtin_amdgcn_mfma_f32_16x16x32_bf16(af[i], bf[j], acc[i][j], 0, 0, 0);
  }

  const int half = N >> 1;
  #pragma unroll
  for (int i = 0; i < 4; ++i) {
    const int mrow = bm + wr + i * 16 + fq * 4;
    #pragma unroll
    for (int j = 0; j < 4; ++j) {
      const int n = bn + wc + j * 16 + fr;
      #pragma unroll
      for (int r = 0; r < 4; ++r) {
        const int m = mrow + r;
        const float v = acc[i][j][r];
        if (MODE == 0) {
          if (n < half) O0[(size_t)m * half + n] = v;
          else          O1[(size_t)m * half + (n - half)] = v;
        } else {
          O0[(size_t)m * N + n] = v + resid[(size_t)m * N + n];
        }
      }
    }
  }
}

// ---------------- 3) depthwise 3x3 conv + bias + SiLU ----------------
__global__ __launch_bounds__(256) void conv_silu_kernel(const float* __restrict__ xpart,
    const float* __restrict__ cw, const float* __restrict__ cb, float* __restrict__ xc) {
  int bl = blockIdx.x;
  int b = bl >> 10, l = bl & 1023;
  int h = l >> 5, w = l & 31;
  for (int d = threadIdx.x; d < DI_; d += 256) {
    float acc = cb[d];
    #pragma unroll
    for (int dy = -1; dy <= 1; ++dy) {
      int hh = h + dy;
      if (hh < 0 || hh >= HW_) continue;
      #pragma unroll
      for (int dx = -1; dx <= 1; ++dx) {
        int ww = w + dx;
        if (ww < 0 || ww >= HW_) continue;
        acc += cw[d * 9 + (dy + 1) * 3 + (dx + 1)] *
               xpart[((size_t)(b << 10) + (hh << 5) + ww) * DI_ + d];
      }
    }
    xc[(size_t)bl * DI_ + d] = acc / (1.0f + __expf(-acc));
  }
}

// ---------------- 4) x_dbl[b,k,p,c] = sum_d xc[b, sp(k,p), d] * xproj[k,c,d] ----------------
__global__ __launch_bounds__(256) void xdbl_kernel(const float* __restrict__ xc,
    const float* __restrict__ xproj, float* __restrict__ xdbl) {
  int blk = blockIdx.x;
  int pt = blk & 63;
  int k  = (blk >> 6) & 3;
  int b  = blk >> 8;
  int p0 = pt * 16;
  __shared__ float Xs[16][64];
  __shared__ float Ws[64][65];
  int lane = threadIdx.x & 63;
  int wv4 = (threadIdx.x >> 6) * 4;
  float acc[4] = {0.f, 0.f, 0.f, 0.f};
  for (int d0 = 0; d0 < DI_; d0 += 64) {
    __syncthreads();
    #pragma unroll
    for (int i = 0; i < 4; ++i) {
      int e = threadIdx.x + i * 256;
      int pi = e >> 6, col = e & 63;
      Xs[pi][col] = xc[((size_t)(b * 1024 + sp_map(k, p0 + pi))) * DI_ + d0 + col];
    }
    #pragma unroll
    for (int i = 0; i < 16; ++i) {
      int e = threadIdx.x + i * 256;
      int dd = e & 63, cc = e >> 6;
      Ws[dd][cc] = xproj[((size_t)(k * 64 + cc)) * DI_ + d0 + dd];
    }
    __syncthreads();
    #pragma unroll
    for (int dc = 0; dc < 64; ++dc) {
      float wval = Ws[dc][lane];
      #pragma unroll
      for (int q = 0; q < 4; ++q) acc[q] += wval * Xs[wv4 + q][dc];
    }
  }
  #pragma unroll
  for (int q = 0; q < 4; ++q) {
    int p = p0 + wv4 + q;
    xdbl[(((size_t)(b * 4 + k)) * 1024 + p) * 64 + lane] = acc[q];
  }
}

// ---------------- 5a) scan pass A: per-chunk local scan + chunk summary ----------------
// grid: (((b*4+k)*NC_+c)*4+dgrp) blocks x 256 thr. thread -> d = dgrp*256+tid.
// st[g*NC_+c][slot]: slot n*64+lane = P[n]; 1024 + n*64+lane = h_end (g=(b*4+k)*16+(d>>6))
__global__ __launch_bounds__(256, 2) void scan_passA(const float* __restrict__ xc,
    const float* __restrict__ xdbl, const float* __restrict__ dtw,
    const float* __restrict__ dtb, const float* __restrict__ Alogs,
    float* __restrict__ st) {
  const int blk = blockIdx.x;
  const int dgrp = blk & 3;
  const int c    = (blk >> 2) & (NC_ - 1);
  const int k    = (blk >> 5) & 3;
  const int b    = blk >> 7;
  const int tid = threadIdx.x;
  const int d = dgrp * 256 + tid;
  const int kd = k * DI_ + d;

  // per-thread dt weights in native float4 registers (no address taken -> no scratch)
  float4 dtwr4[8];
  #pragma unroll
  for (int r = 0; r < 8; ++r)
    dtwr4[r] = ((const float4*)(dtw + (size_t)kd * 32))[r];
  float A[16], h[16];
  #pragma unroll
  for (int n = 0; n < 16; ++n) {
    A[n] = -__expf(Alogs[(size_t)kd * 16 + n]);
    h[n] = 0.f;
  }
  const float bias = dtb[kd];
  float S = 0.f;

  __shared__ __align__(16) float Ls[16 * 64];
  const float* xrow = xdbl + ((size_t)((b * 4 + k) * 1024 + c * CL_)) * 64;
  const float* xcb  = xc + ((size_t)b << 20) + d;   // + sp*1024 per step
  const int p0g = c * CL_;

  for (int pt = 0; pt < CL_; pt += 16) {
    __syncthreads();
    ((float4*)Ls)[tid] = ((const float4*)(xrow + pt * 64))[tid];
    __syncthreads();
    #pragma unroll
    for (int pp = 0; pp < 16; ++pp) {
      const float* row = Ls + pp * 64;
      int sp = sp_map(k, p0g + pt + pp);
      float u = xcb[sp << 10];
      float dtr = bias;
      #pragma unroll
      for (int r4 = 0; r4 < 8; ++r4) {
        float4 rv = ((const float4*)row)[r4];
        dtr += dtwr4[r4].x * rv.x + dtwr4[r4].y * rv.y +
               dtwr4[r4].z * rv.z + dtwr4[r4].w * rv.w;
      }
      float dt = softplus_fast(dtr);
      S += dt;
      float dtu = dt * u;
      #pragma unroll
      for (int n4 = 0; n4 < 4; ++n4) {
        float4 bv = ((const float4*)(row + 32))[n4];
        h[n4 * 4 + 0] = h[n4 * 4 + 0] * __expf(dt * A[n4 * 4 + 0]) + dtu * bv.x;
        h[n4 * 4 + 1] = h[n4 * 4 + 1] * __expf(dt * A[n4 * 4 + 1]) + dtu * bv.y;
        h[n4 * 4 + 2] = h[n4 * 4 + 2] * __expf(dt * A[n4 * 4 + 2]) + dtu * bv.z;
        h[n4 * 4 + 3] = h[n4 * 4 + 3] * __expf(dt * A[n4 * 4 + 3]) + dtu * bv.w;
      }
    }
  }
  const int g = (b * 4 + k) * 16 + (d >> 6);
  const int lane = d & 63;
  size_t base = ((size_t)g * NC_ + c) * 2048;
  #pragma unroll
  for (int n = 0; n < 16; ++n) {
    st[base + n * 64 + lane]        = __expf(A[n] * S);
    st[base + 1024 + n * 64 + lane] = h[n];
  }
}

// ---------------- 5b) combine chunk states; overwrite h-slot with H_in(c) ----------------
__global__ __launch_bounds__(256) void scan_mid(float* __restrict__ st) {
  int idx = blockIdx.x * 256 + threadIdx.x;   // 32768 threads: (g, lane)
  int lane = idx & 63;
  int g = idx >> 6;
  float H[16];
  #pragma unroll
  for (int n = 0; n < 16; ++n) H[n] = 0.f;
  for (int c = 0; c < NC_; ++c) {
    size_t base = ((size_t)g * NC_ + c) * 2048;
    #pragma unroll
    for (int n = 0; n < 16; ++n) {
      float P  = st[base + n * 64 + lane];
      float he = st[base + 1024 + n * 64 + lane];
      st[base + 1024 + n * 64 + lane] = H[n];           // H_in for chunk c
      H[n] = he + P * H[n];
    }
  }
}

// ---------------- 5c) scan pass B: rescan chunk from H_in, emit y ----------------
__global__ __launch_bounds__(256, 2) void scan_passB(const float* __restrict__ xc,
    const float* __restrict__ xdbl, const float* __restrict__ dtw,
    const float* __restrict__ dtb, const float* __restrict__ Alogs,
    const float* __restrict__ Ds, const float* __restrict__ st,
    __hip_bfloat16* __restrict__ ys) {
  const int blk = blockIdx.x;
  const int dgrp = blk & 3;
  const int c    = (blk >> 2) & (NC_ - 1);
  const int k    = (blk >> 5) & 3;
  const int b    = blk >> 7;
  const int tid = threadIdx.x;
  const int d = dgrp * 256 + tid;
  const int kd = k * DI_ + d;

  float4 dtwr4[8];
  #pragma unroll
  for (int r = 0; r < 8; ++r)
    dtwr4[r] = ((const float4*)(dtw + (size_t)kd * 32))[r];
  const int g = (b * 4 + k) * 16 + (d >> 6);
  const int lane = d & 63;
  const size_t sbase = ((size_t)g * NC_ + c) * 2048;
  float A[16], h[16];
  #pragma unroll
  for (int n = 0; n < 16; ++n) {
    A[n] = -__expf(Alogs[(size_t)kd * 16 + n]);
    h[n] = st[sbase + 1024 + n * 64 + lane];
  }
  const float bias = dtb[kd];
  const float Dv = Ds[kd];

  __shared__ __align__(16) float Ls[16 * 64];
  const float* xrow = xdbl + ((size_t)((b * 4 + k) * 1024 + c * CL_)) * 64;
  const float* xcb  = xc + ((size_t)b << 20) + d;
  __hip_bfloat16* ysb = ys + ((size_t)(b << 12) + k) * 1024 + d;  // + sp*4096 per step
  const int p0g = c * CL_;

  for (int pt = 0; pt < CL_; pt += 16) {
    __syncthreads();
    ((float4*)Ls)[tid] = ((const float4*)(xrow + pt * 64))[tid];
    __syncthreads();
    #pragma unroll
    for (int pp = 0; pp < 16; ++pp) {
      const float* row = Ls + pp * 64;
      int sp = sp_map(k, p0g + pt + pp);
      float u = xcb[sp << 10];
      float dtr = bias;
      #pragma unroll
      for (int r4 = 0; r4 < 8; ++r4) {
        float4 rv = ((const float4*)row)[r4];
        dtr += dtwr4[r4].x * rv.x + dtwr4[r4].y * rv.y +
               dtwr4[r4].z * rv.z + dtwr4[r4].w * rv.w;
      }
      float dt = softplus_fast(dtr);
      float dtu = dt * u;
      float y = 0.f;
      #pragma unroll
      for (int n4 = 0; n4 < 4; ++n4) {
        float4 bv = ((const float4*)(row + 32))[n4];
        float4 cv = ((const float4*)(row + 48))[n4];
        h[n4 * 4 + 0] = h[n4 * 4 + 0] * __expf(dt * A[n4 * 4 + 0]) + dtu * bv.x;
        h[n4 * 4 + 1] = h[n4 * 4 + 1] * __expf(dt * A[n4 * 4 + 1]) + dtu * bv.y;
        h[n4 * 4 + 2] = h[n4 * 4 + 2] * __expf(dt * A[n4 * 4 + 2]) + dtu * bv.z;
        h[n4 * 4 + 3] = h[n4 * 4 + 3] * __expf(dt * A[n4 * 4 + 3]) + dtu * bv.w;
        y += h[n4 * 4 + 0] * cv.x + h[n4 * 4 + 1] * cv.y +
             h[n4 * 4 + 2] * cv.z + h[n4 * 4 + 3] * cv.w;
      }
      y += Dv * u;
      ysb[(size_t)sp << 12] = __float2bfloat16(y);
    }
  }
}

// ---------------- 6) merge(sum k) + LayerNorm(DI) + SiLU(z) gate (emits bf16) ----------------
__global__ __launch_bounds__(256) void merge_kernel(const __hip_bfloat16* __restrict__ ys,
    const float* __restrict__ z, const float* __restrict__ ow, const float* __restrict__ ob,
    __hip_bfloat16* __restrict__ ym) {
  int bl = blockIdx.x;
  int t = threadIdx.x;
  float v[4];
  float s = 0.f;
  #pragma unroll
  for (int i = 0; i < 4; ++i) {
    int d = t + i * 256;
    float acc = 0.f;
    #pragma unroll
    for (int kk = 0; kk < 4; ++kk)
      acc += __bfloat162float(ys[(((size_t)bl) * 4 + kk) * DI_ + d]);
    v[i] = acc;
    s += acc;
  }
  __shared__ float sm[4];
  float tot = block_sum_256(s, sm);
  float mu = tot * (1.0f / DI_);
  float q = 0.f;
  #pragma unroll
  for (int i = 0; i < 4; ++i) { float dv = v[i] - mu; q += dv * dv; }
  float qs = block_sum_256(q, sm);
  float rs = rsqrtf(qs * (1.0f / DI_) + 1e-5f);
  #pragma unroll
  for (int i = 0; i < 4; ++i) {
    int d = t + i * 256;
    float ln = (v[i] - mu) * rs * ow[d] + ob[d];
    float zv = z[(size_t)bl * DI_ + d];
    ym[(size_t)bl * DI_ + d] = __float2bfloat16(ln * (zv / (1.0f + __expf(-zv))));
  }
}

// ---------------- launcher ----------------
extern "C" void kernel_launch(void* const* d_in, const int* in_sizes, int n_in,
                              void* d_out, int out_size, void* d_ws, size_t ws_size,
                              hipStream_t stream) {
  const float* x         = (const float*)d_in[0];
  const float* norm_w    = (const float*)d_in[1];
  const float* norm_b    = (const float*)d_in[2];
  const float* in_proj_w = (const float*)d_in[3];
  const float* conv_w    = (const float*)d_in[4];
  const float* conv_b    = (const float*)d_in[5];
  const float* x_proj_w  = (const float*)d_in[6];
  const float* dt_projs_w= (const float*)d_in[7];
  const float* dt_projs_b= (const float*)d_in[8];
  const float* A_logs    = (const float*)d_in[9];
  const float* Ds        = (const float*)d_in[10];
  const float* out_norm_w= (const float*)d_in[11];
  const float* out_norm_b= (const float*)d_in[12];
  const float* out_proj_w= (const float*)d_in[13];
  float* out = (float*)d_out;

  // workspace layout (liveness-packed, total 187,695,104 B)
  char* ws = (char*)d_ws;
  float* z              = (float*)(ws);                         // 33.55 MB [GEMM1..merge]
  float* xc             = (float*)(ws + 33554432ULL);           // 33.55 MB [conv..passB]
  float* xpart          = (float*)(ws + 67108864ULL);           // 33.55 MB [GEMM1..conv]
  float* st             = xpart;                                //          [passA..passB]
  __hip_bfloat16* ymb   = (__hip_bfloat16*)xpart;               // 16.8 MB  [merge..GEMM2]
  float* xdbl           = (float*)(ws + 100663296ULL);          //  8.39 MB [xdbl..passB]
  __hip_bfloat16* ys    = (__hip_bfloat16*)(ws + 109051904ULL); // 67.11 MB [passB..merge]
  __hip_bfloat16* xnb   = (__hip_bfloat16*)(ws + 176160768ULL); //  8.39 MB [ln..GEMM1]
  __hip_bfloat16* w1b   = (__hip_bfloat16*)(ws + 184549376ULL); //  2.10 MB [cast..GEMM1]
  __hip_bfloat16* w2b   = (__hip_bfloat16*)(ws + 186646528ULL); //  1.05 MB [cast..GEMM2]

  // 0) weight casts
  cast_bf16_kernel<<<1024, 256, 0, stream>>>(in_proj_w, w1b, (2048 * 512) / 4);
  cast_bf16_kernel<<<512, 256, 0, stream>>>(out_proj_w, w2b, (512 * 1024) / 4);
  // 1) LayerNorm (bf16 out)
  ln_kernel<<<M_, 256, 0, stream>>>(x, norm_w, norm_b, xnb);
  // 2) xz = xn @ in_proj_w.T  (MFMA) -> split xpart | z (f32)
  gemm_bf16<0><<<dim3(2048 / 128, M_ / 128), 256, 0, stream>>>(
      xnb, w1b, M_, 2048, C_, xpart, z, nullptr);
  // 3) depthwise conv + SiLU
  conv_silu_kernel<<<M_, 256, 0, stream>>>(xpart, conv_w, conv_b, xc);
  // 4) x_dbl projections
  xdbl_kernel<<<B_ * K_ * 64, 256, 0, stream>>>(xc, x_proj_w, xdbl);
  // 5) chunked parallel selective scan (256-thread blocks, 16-row staging)
  scan_passA<<<B_ * K_ * NC_ * 4, 256, 0, stream>>>(
      xc, xdbl, dt_projs_w, dt_projs_b, A_logs, st);
  scan_mid<<<(B_ * K_ * DI_) / 256, 256, 0, stream>>>(st);
  scan_passB<<<B_ * K_ * NC_ * 4, 256, 0, stream>>>(
      xc, xdbl, dt_projs_w, dt_projs_b, A_logs, Ds, st, ys);
  // 6) merge + out-LN + SiLU(z) gate (bf16 out)
  merge_kernel<<<M_, 256, 0, stream>>>(ys, z, out_norm_w, out_norm_b, ymb);
  // 7) out = ym @ out_proj_w.T + resid (MFMA)
  gemm_bf16<1><<<dim3(C_ / 128, M_ / 128), 256, 0, stream>>>(
      ymb, w2b, M_, C_, DI_, out, nullptr, x);
}

// Round 6
// 735.090 us; speedup vs baseline: 4.1418x; 4.0080x over previous
//
#include <hip/hip_runtime.h>
#include <hip/hip_bf16.h>

// Problem constants
#define B_   8
#define L_   1024
#define C_   512
#define DI_  1024
#define K_   4
#define N_   16
#define R_   32
#define HW_  32
#define M_   (B_ * L_)   // 8192 rows
#define NC_  8           // scan chunks
#define CL_  128         // chunk length = L_/NC_

typedef __attribute__((ext_vector_type(8))) short short8;   // 8 bf16 (4 VGPRs)
typedef __attribute__((ext_vector_type(4))) float f32x4;

__device__ __forceinline__ void gload_lds16(const void* g, void* l) {
  __builtin_amdgcn_global_load_lds(
      (const __attribute__((address_space(1))) void*)g,
      (__attribute__((address_space(3))) void*)l, 16, 0, 0);
}

// Map scan position p -> spatial index l (same map for gather of u and scatter of y)
__device__ __forceinline__ int sp_map(int k, int p) {
  if (k == 0) return p;
  if (k == 1) return ((p & 31) << 5) | (p >> 5);      // (p%H)*W + p/H
  if (k == 2) return 1023 - p;
  int q = 1023 - p;
  return ((q & 31) << 5) | (q >> 5);
}

__device__ __forceinline__ float softplus_fast(float x) {
  return (x > 20.f) ? x : __logf(1.f + __expf(x));
}

__device__ __forceinline__ float dot4(float4 a, float4 b) {
  return a.x * b.x + a.y * b.y + a.z * b.z + a.w * b.w;
}

__device__ __forceinline__ float4 negexp4(float4 v) {
  return make_float4(-__expf(v.x), -__expf(v.y), -__expf(v.z), -__expf(v.w));
}

// h = h * exp(dt*a) + dtu*b   (elementwise, pure SSA — no arrays anywhere)
__device__ __forceinline__ float4 hupd4(float4 h, float dt, float4 a, float dtu, float4 b) {
  h.x = h.x * __expf(dt * a.x) + dtu * b.x;
  h.y = h.y * __expf(dt * a.y) + dtu * b.y;
  h.z = h.z * __expf(dt * a.z) + dtu * b.z;
  h.w = h.w * __expf(dt * a.w) + dtu * b.w;
  return h;
}

__device__ __forceinline__ float block_sum_256(float v, float* sm) {
  #pragma unroll
  for (int o = 32; o > 0; o >>= 1) v += __shfl_down(v, o);
  int wid = threadIdx.x >> 6;
  if ((threadIdx.x & 63) == 0) sm[wid] = v;
  __syncthreads();
  float r = sm[0] + sm[1] + sm[2] + sm[3];
  __syncthreads();
  return r;
}

// ---------------- weight cast f32 -> bf16 (vectorized) ----------------
__global__ __launch_bounds__(256) void cast_bf16_kernel(const float* __restrict__ in,
    __hip_bfloat16* __restrict__ out, int n4) {
  int i = blockIdx.x * 256 + threadIdx.x;
  if (i >= n4) return;
  float4 v = ((const float4*)in)[i];
  union { __hip_bfloat16 h[4]; short4 s; } pk;
  pk.h[0] = __float2bfloat16(v.x); pk.h[1] = __float2bfloat16(v.y);
  pk.h[2] = __float2bfloat16(v.z); pk.h[3] = __float2bfloat16(v.w);
  ((short4*)out)[i] = pk.s;
}

// ---------------- 1) LayerNorm over C=512 (emits bf16) ----------------
__global__ __launch_bounds__(256) void ln_kernel(const float* __restrict__ x,
    const float* __restrict__ w, const float* __restrict__ b,
    __hip_bfloat16* __restrict__ xn) {
  int row = blockIdx.x;
  const float* xr = x + (size_t)row * C_;
  int t = threadIdx.x;
  float v0 = xr[t], v1 = xr[t + 256];
  __shared__ float sm[4];
  float s = block_sum_256(v0 + v1, sm);
  float mu = s * (1.0f / C_);
  float d0 = v0 - mu, d1 = v1 - mu;
  float q = block_sum_256(d0 * d0 + d1 * d1, sm);
  float rs = rsqrtf(q * (1.0f / C_) + 1e-5f);
  __hip_bfloat16* xo = xn + (size_t)row * C_;
  xo[t]       = __float2bfloat16(d0 * rs * w[t] + b[t]);
  xo[t + 256] = __float2bfloat16(d1 * rs * w[t + 256] + b[t + 256]);
}

// ---------------- bf16 MFMA GEMM: C[m,n] = sum_k A[m,k]*Bw[n,k] ----------------
template <int MODE>
__global__ __launch_bounds__(256) void gemm_bf16(
    const __hip_bfloat16* __restrict__ A, const __hip_bfloat16* __restrict__ Bw,
    const int M, const int N, const int K,
    float* __restrict__ O0, float* __restrict__ O1, const float* __restrict__ resid) {
  __shared__ __align__(16) __hip_bfloat16 Asm[128][32];  // 8 KB, linear (global_load_lds dest)
  __shared__ __align__(16) __hip_bfloat16 Bsm[128][32];  // 8 KB
  const int bm = blockIdx.y * 128, bn = blockIdx.x * 128;
  const int tid = threadIdx.x, lane = tid & 63, wid = tid >> 6;
  const int wr = (wid >> 1) * 64, wc = (wid & 1) * 64;   // wave's 64x64 output origin
  const int fr = lane & 15, fq = lane >> 4;

  f32x4 acc[4][4] = {};

  const int r0 = tid >> 2, c0 = (tid & 3) * 8;
  const int r1 = (tid + 256) >> 2;
  const __hip_bfloat16* Ag0 = A + (size_t)(bm + r0) * K + c0;
  const __hip_bfloat16* Ag1 = A + (size_t)(bm + r1) * K + c0;
  const __hip_bfloat16* Bg0 = Bw + (size_t)(bn + r0) * K + c0;
  const __hip_bfloat16* Bg1 = Bw + (size_t)(bn + r1) * K + c0;
  char* ldsA0 = (char*)Asm + wid * 1024;          // wave-uniform base; HW adds lane*16
  char* ldsA1 = (char*)Asm + 4096 + wid * 1024;
  char* ldsB0 = (char*)Bsm + wid * 1024;
  char* ldsB1 = (char*)Bsm + 4096 + wid * 1024;

  for (int k0 = 0; k0 < K; k0 += 32) {
    __syncthreads();
    gload_lds16(Ag0 + k0, ldsA0);
    gload_lds16(Ag1 + k0, ldsA1);
    gload_lds16(Bg0 + k0, ldsB0);
    gload_lds16(Bg1 + k0, ldsB1);
    __syncthreads();

    short8 af[4], bf[4];
    #pragma unroll
    for (int i = 0; i < 4; ++i) {
      af[i] = *(const short8*)((const char*)Asm + (wr + i * 16 + fr) * 64 + fq * 16);
      bf[i] = *(const short8*)((const char*)Bsm + (wc + i * 16 + fr) * 64 + fq * 16);
    }
    #pragma unroll
    for (int i = 0; i < 4; ++i)
      #pragma unroll
      for (int j = 0; j < 4; ++j)
        acc[i][j] = __builtin_amdgcn_mfma_f32_16x16x32_bf16(af[i], bf[j], acc[i][j], 0, 0, 0);
  }

  const int half = N >> 1;
  #pragma unroll
  for (int i = 0; i < 4; ++i) {
    const int mrow = bm + wr + i * 16 + fq * 4;
    #pragma unroll
    for (int j = 0; j < 4; ++j) {
      const int n = bn + wc + j * 16 + fr;
      #pragma unroll
      for (int r = 0; r < 4; ++r) {
        const int m = mrow + r;
        const float v = acc[i][j][r];
        if (MODE == 0) {
          if (n < half) O0[(size_t)m * half + n] = v;
          else          O1[(size_t)m * half + (n - half)] = v;
        } else {
          O0[(size_t)m * N + n] = v + resid[(size_t)m * N + n];
        }
      }
    }
  }
}

// ---------------- 3) depthwise 3x3 conv + bias + SiLU ----------------
__global__ __launch_bounds__(256) void conv_silu_kernel(const float* __restrict__ xpart,
    const float* __restrict__ cw, const float* __restrict__ cb, float* __restrict__ xc) {
  int bl = blockIdx.x;
  int b = bl >> 10, l = bl & 1023;
  int h = l >> 5, w = l & 31;
  for (int d = threadIdx.x; d < DI_; d += 256) {
    float acc = cb[d];
    #pragma unroll
    for (int dy = -1; dy <= 1; ++dy) {
      int hh = h + dy;
      if (hh < 0 || hh >= HW_) continue;
      #pragma unroll
      for (int dx = -1; dx <= 1; ++dx) {
        int ww = w + dx;
        if (ww < 0 || ww >= HW_) continue;
        acc += cw[d * 9 + (dy + 1) * 3 + (dx + 1)] *
               xpart[((size_t)(b << 10) + (hh << 5) + ww) * DI_ + d];
      }
    }
    xc[(size_t)bl * DI_ + d] = acc / (1.0f + __expf(-acc));
  }
}

// ---------------- 4) x_dbl[b,k,p,c] = sum_d xc[b, sp(k,p), d] * xproj[k,c,d] ----------------
__global__ __launch_bounds__(256) void xdbl_kernel(const float* __restrict__ xc,
    const float* __restrict__ xproj, float* __restrict__ xdbl) {
  int blk = blockIdx.x;
  int pt = blk & 63;
  int k  = (blk >> 6) & 3;
  int b  = blk >> 8;
  int p0 = pt * 16;
  __shared__ float Xs[16][64];
  __shared__ float Ws[64][65];
  int lane = threadIdx.x & 63;
  int wv4 = (threadIdx.x >> 6) * 4;
  float acc[4] = {0.f, 0.f, 0.f, 0.f};
  for (int d0 = 0; d0 < DI_; d0 += 64) {
    __syncthreads();
    #pragma unroll
    for (int i = 0; i < 4; ++i) {
      int e = threadIdx.x + i * 256;
      int pi = e >> 6, col = e & 63;
      Xs[pi][col] = xc[((size_t)(b * 1024 + sp_map(k, p0 + pi))) * DI_ + d0 + col];
    }
    #pragma unroll
    for (int i = 0; i < 16; ++i) {
      int e = threadIdx.x + i * 256;
      int dd = e & 63, cc = e >> 6;
      Ws[dd][cc] = xproj[((size_t)(k * 64 + cc)) * DI_ + d0 + dd];
    }
    __syncthreads();
    #pragma unroll
    for (int dc = 0; dc < 64; ++dc) {
      float wval = Ws[dc][lane];
      #pragma unroll
      for (int q = 0; q < 4; ++q) acc[q] += wval * Xs[wv4 + q][dc];
    }
  }
  #pragma unroll
  for (int q = 0; q < 4; ++q) {
    int p = p0 + wv4 + q;
    xdbl[(((size_t)(b * 4 + k)) * 1024 + p) * 64 + lane] = acc[q];
  }
}

// ---------------- 5a) scan pass A: per-chunk local scan + chunk summary ----------------
// grid: (((b*4+k)*NC_+c)*4+dgrp) blocks x 256 thr. thread -> d = dgrp*256+tid.
// ZERO local arrays: all state in named float4 SSA values (spill-proof).
__global__ __launch_bounds__(256, 2) void scan_passA(const float* __restrict__ xc,
    const float* __restrict__ xdbl, const float* __restrict__ dtw,
    const float* __restrict__ dtb, const float* __restrict__ Alogs,
    float* __restrict__ st) {
  const int blk = blockIdx.x;
  const int dgrp = blk & 3;
  const int c    = (blk >> 2) & (NC_ - 1);
  const int k    = (blk >> 5) & 3;
  const int b    = blk >> 7;
  const int tid = threadIdx.x;
  const int d = dgrp * 256 + tid;
  const int kd = k * DI_ + d;

  const float4* Wp = (const float4*)(dtw + (size_t)kd * 32);
  float4 wq0 = Wp[0], wq1 = Wp[1], wq2 = Wp[2], wq3 = Wp[3];
  float4 wq4 = Wp[4], wq5 = Wp[5], wq6 = Wp[6], wq7 = Wp[7];
  const float4* Ap = (const float4*)(Alogs + (size_t)kd * 16);
  float4 aq0 = negexp4(Ap[0]), aq1 = negexp4(Ap[1]);
  float4 aq2 = negexp4(Ap[2]), aq3 = negexp4(Ap[3]);
  float4 hq0 = make_float4(0.f, 0.f, 0.f, 0.f), hq1 = hq0, hq2 = hq0, hq3 = hq0;
  const float bias = dtb[kd];
  float S = 0.f;

  __shared__ __align__(16) float Ls[16 * 64];
  const float* xrow = xdbl + ((size_t)((b * 4 + k) * 1024 + c * CL_)) * 64;
  const float* xcb  = xc + ((size_t)b << 20) + d;   // + sp*1024 per step
  const int p0g = c * CL_;

  for (int pt = 0; pt < CL_; pt += 16) {
    __syncthreads();
    ((float4*)Ls)[tid] = ((const float4*)(xrow + pt * 64))[tid];
    __syncthreads();
    #pragma unroll 4
    for (int pp = 0; pp < 16; ++pp) {
      const float* row = Ls + pp * 64;
      float4 r0 = ((const float4*)row)[0], r1 = ((const float4*)row)[1];
      float4 r2 = ((const float4*)row)[2], r3 = ((const float4*)row)[3];
      float4 r4 = ((const float4*)row)[4], r5 = ((const float4*)row)[5];
      float4 r6 = ((const float4*)row)[6], r7 = ((const float4*)row)[7];
      float dtr = bias + dot4(wq0, r0) + dot4(wq1, r1) + dot4(wq2, r2) + dot4(wq3, r3)
                       + dot4(wq4, r4) + dot4(wq5, r5) + dot4(wq6, r6) + dot4(wq7, r7);
      float dt = softplus_fast(dtr);
      S += dt;
      int sp = sp_map(k, p0g + pt + pp);
      float u = xcb[sp << 10];
      float dtu = dt * u;
      float4 b0 = ((const float4*)(row + 32))[0], b1 = ((const float4*)(row + 32))[1];
      float4 b2 = ((const float4*)(row + 32))[2], b3 = ((const float4*)(row + 32))[3];
      hq0 = hupd4(hq0, dt, aq0, dtu, b0);
      hq1 = hupd4(hq1, dt, aq1, dtu, b1);
      hq2 = hupd4(hq2, dt, aq2, dtu, b2);
      hq3 = hupd4(hq3, dt, aq3, dtu, b3);
    }
  }
  const int g = (b * 4 + k) * 16 + (d >> 6);
  const int lane = d & 63;
  size_t base = ((size_t)g * NC_ + c) * 2048 + lane;
  st[base +  0 * 64] = __expf(aq0.x * S);  st[base +  1 * 64] = __expf(aq0.y * S);
  st[base +  2 * 64] = __expf(aq0.z * S);  st[base +  3 * 64] = __expf(aq0.w * S);
  st[base +  4 * 64] = __expf(aq1.x * S);  st[base +  5 * 64] = __expf(aq1.y * S);
  st[base +  6 * 64] = __expf(aq1.z * S);  st[base +  7 * 64] = __expf(aq1.w * S);
  st[base +  8 * 64] = __expf(aq2.x * S);  st[base +  9 * 64] = __expf(aq2.y * S);
  st[base + 10 * 64] = __expf(aq2.z * S);  st[base + 11 * 64] = __expf(aq2.w * S);
  st[base + 12 * 64] = __expf(aq3.x * S);  st[base + 13 * 64] = __expf(aq3.y * S);
  st[base + 14 * 64] = __expf(aq3.z * S);  st[base + 15 * 64] = __expf(aq3.w * S);
  float* hb = st + base + 1024;
  hb[ 0 * 64] = hq0.x; hb[ 1 * 64] = hq0.y; hb[ 2 * 64] = hq0.z; hb[ 3 * 64] = hq0.w;
  hb[ 4 * 64] = hq1.x; hb[ 5 * 64] = hq1.y; hb[ 6 * 64] = hq1.z; hb[ 7 * 64] = hq1.w;
  hb[ 8 * 64] = hq2.x; hb[ 9 * 64] = hq2.y; hb[10 * 64] = hq2.z; hb[11 * 64] = hq2.w;
  hb[12 * 64] = hq3.x; hb[13 * 64] = hq3.y; hb[14 * 64] = hq3.z; hb[15 * 64] = hq3.w;
}

// ---------------- 5b) combine chunk states; overwrite h-slot with H_in(c) ----------------
__global__ __launch_bounds__(256) void scan_mid(float* __restrict__ st) {
  int idx = blockIdx.x * 256 + threadIdx.x;   // 32768 threads: (g, lane)
  int lane = idx & 63;
  int g = idx >> 6;
  float H[16];
  #pragma unroll
  for (int n = 0; n < 16; ++n) H[n] = 0.f;
  for (int c = 0; c < NC_; ++c) {
    size_t base = ((size_t)g * NC_ + c) * 2048;
    #pragma unroll
    for (int n = 0; n < 16; ++n) {
      float P  = st[base + n * 64 + lane];
      float he = st[base + 1024 + n * 64 + lane];
      st[base + 1024 + n * 64 + lane] = H[n];           // H_in for chunk c
      H[n] = he + P * H[n];
    }
  }
}

// ---------------- 5c) scan pass B: rescan chunk from H_in, emit y ----------------
__global__ __launch_bounds__(256, 2) void scan_passB(const float* __restrict__ xc,
    const float* __restrict__ xdbl, const float* __restrict__ dtw,
    const float* __restrict__ dtb, const float* __restrict__ Alogs,
    const float* __restrict__ Ds, const float* __restrict__ st,
    __hip_bfloat16* __restrict__ ys) {
  const int blk = blockIdx.x;
  const int dgrp = blk & 3;
  const int c    = (blk >> 2) & (NC_ - 1);
  const int k    = (blk >> 5) & 3;
  const int b    = blk >> 7;
  const int tid = threadIdx.x;
  const int d = dgrp * 256 + tid;
  const int kd = k * DI_ + d;

  const float4* Wp = (const float4*)(dtw + (size_t)kd * 32);
  float4 wq0 = Wp[0], wq1 = Wp[1], wq2 = Wp[2], wq3 = Wp[3];
  float4 wq4 = Wp[4], wq5 = Wp[5], wq6 = Wp[6], wq7 = Wp[7];
  const float4* Ap = (const float4*)(Alogs + (size_t)kd * 16);
  float4 aq0 = negexp4(Ap[0]), aq1 = negexp4(Ap[1]);
  float4 aq2 = negexp4(Ap[2]), aq3 = negexp4(Ap[3]);

  const int g = (b * 4 + k) * 16 + (d >> 6);
  const int lane = d & 63;
  const float* hb = st + ((size_t)g * NC_ + c) * 2048 + 1024 + lane;
  float4 hq0 = make_float4(hb[0 * 64], hb[1 * 64], hb[2 * 64], hb[3 * 64]);
  float4 hq1 = make_float4(hb[4 * 64], hb[5 * 64], hb[6 * 64], hb[7 * 64]);
  float4 hq2 = make_float4(hb[8 * 64], hb[9 * 64], hb[10 * 64], hb[11 * 64]);
  float4 hq3 = make_float4(hb[12 * 64], hb[13 * 64], hb[14 * 64], hb[15 * 64]);
  const float bias = dtb[kd];
  const float Dv = Ds[kd];

  __shared__ __align__(16) float Ls[16 * 64];
  const float* xrow = xdbl + ((size_t)((b * 4 + k) * 1024 + c * CL_)) * 64;
  const float* xcb  = xc + ((size_t)b << 20) + d;
  __hip_bfloat16* ysb = ys + ((size_t)(b << 12) + k) * 1024 + d;  // + sp*4096 per step
  const int p0g = c * CL_;

  for (int pt = 0; pt < CL_; pt += 16) {
    __syncthreads();
    ((float4*)Ls)[tid] = ((const float4*)(xrow + pt * 64))[tid];
    __syncthreads();
    #pragma unroll 4
    for (int pp = 0; pp < 16; ++pp) {
      const float* row = Ls + pp * 64;
      float4 r0 = ((const float4*)row)[0], r1 = ((const float4*)row)[1];
      float4 r2 = ((const float4*)row)[2], r3 = ((const float4*)row)[3];
      float4 r4 = ((const float4*)row)[4], r5 = ((const float4*)row)[5];
      float4 r6 = ((const float4*)row)[6], r7 = ((const float4*)row)[7];
      float dtr = bias + dot4(wq0, r0) + dot4(wq1, r1) + dot4(wq2, r2) + dot4(wq3, r3)
                       + dot4(wq4, r4) + dot4(wq5, r5) + dot4(wq6, r6) + dot4(wq7, r7);
      float dt = softplus_fast(dtr);
      int sp = sp_map(k, p0g + pt + pp);
      float u = xcb[sp << 10];
      float dtu = dt * u;
      float4 b0 = ((const float4*)(row + 32))[0], b1 = ((const float4*)(row + 32))[1];
      float4 b2 = ((const float4*)(row + 32))[2], b3 = ((const float4*)(row + 32))[3];
      float4 c0 = ((const float4*)(row + 48))[0], c1 = ((const float4*)(row + 48))[1];
      float4 c2 = ((const float4*)(row + 48))[2], c3 = ((const float4*)(row + 48))[3];
      hq0 = hupd4(hq0, dt, aq0, dtu, b0);
      hq1 = hupd4(hq1, dt, aq1, dtu, b1);
      hq2 = hupd4(hq2, dt, aq2, dtu, b2);
      hq3 = hupd4(hq3, dt, aq3, dtu, b3);
      float y = dot4(hq0, c0) + dot4(hq1, c1) + dot4(hq2, c2) + dot4(hq3, c3) + Dv * u;
      ysb[(size_t)sp << 12] = __float2bfloat16(y);
    }
  }
}

// ---------------- 6) merge(sum k) + LayerNorm(DI) + SiLU(z) gate (emits bf16) ----------------
__global__ __launch_bounds__(256) void merge_kernel(const __hip_bfloat16* __restrict__ ys,
    const float* __restrict__ z, const float* __restrict__ ow, const float* __restrict__ ob,
    __hip_bfloat16* __restrict__ ym) {
  int bl = blockIdx.x;
  int t = threadIdx.x;
  float v[4];
  float s = 0.f;
  #pragma unroll
  for (int i = 0; i < 4; ++i) {
    int d = t + i * 256;
    float acc = 0.f;
    #pragma unroll
    for (int kk = 0; kk < 4; ++kk)
      acc += __bfloat162float(ys[(((size_t)bl) * 4 + kk) * DI_ + d]);
    v[i] = acc;
    s += acc;
  }
  __shared__ float sm[4];
  float tot = block_sum_256(s, sm);
  float mu = tot * (1.0f / DI_);
  float q = 0.f;
  #pragma unroll
  for (int i = 0; i < 4; ++i) { float dv = v[i] - mu; q += dv * dv; }
  float qs = block_sum_256(q, sm);
  float rs = rsqrtf(qs * (1.0f / DI_) + 1e-5f);
  #pragma unroll
  for (int i = 0; i < 4; ++i) {
    int d = t + i * 256;
    float ln = (v[i] - mu) * rs * ow[d] + ob[d];
    float zv = z[(size_t)bl * DI_ + d];
    ym[(size_t)bl * DI_ + d] = __float2bfloat16(ln * (zv / (1.0f + __expf(-zv))));
  }
}

// ---------------- launcher ----------------
extern "C" void kernel_launch(void* const* d_in, const int* in_sizes, int n_in,
                              void* d_out, int out_size, void* d_ws, size_t ws_size,
                              hipStream_t stream) {
  const float* x         = (const float*)d_in[0];
  const float* norm_w    = (const float*)d_in[1];
  const float* norm_b    = (const float*)d_in[2];
  const float* in_proj_w = (const float*)d_in[3];
  const float* conv_w    = (const float*)d_in[4];
  const float* conv_b    = (const float*)d_in[5];
  const float* x_proj_w  = (const float*)d_in[6];
  const float* dt_projs_w= (const float*)d_in[7];
  const float* dt_projs_b= (const float*)d_in[8];
  const float* A_logs    = (const float*)d_in[9];
  const float* Ds        = (const float*)d_in[10];
  const float* out_norm_w= (const float*)d_in[11];
  const float* out_norm_b= (const float*)d_in[12];
  const float* out_proj_w= (const float*)d_in[13];
  float* out = (float*)d_out;

  // workspace layout (liveness-packed, total 187,695,104 B)
  char* ws = (char*)d_ws;
  float* z              = (float*)(ws);                         // 33.55 MB [GEMM1..merge]
  float* xc             = (float*)(ws + 33554432ULL);           // 33.55 MB [conv..passB]
  float* xpart          = (float*)(ws + 67108864ULL);           // 33.55 MB [GEMM1..conv]
  float* st             = xpart;                                //          [passA..passB]
  __hip_bfloat16* ymb   = (__hip_bfloat16*)xpart;               // 16.8 MB  [merge..GEMM2]
  float* xdbl           = (float*)(ws + 100663296ULL);          //  8.39 MB [xdbl..passB]
  __hip_bfloat16* ys    = (__hip_bfloat16*)(ws + 109051904ULL); // 67.11 MB [passB..merge]
  __hip_bfloat16* xnb   = (__hip_bfloat16*)(ws + 176160768ULL); //  8.39 MB [ln..GEMM1]
  __hip_bfloat16* w1b   = (__hip_bfloat16*)(ws + 184549376ULL); //  2.10 MB [cast..GEMM1]
  __hip_bfloat16* w2b   = (__hip_bfloat16*)(ws + 186646528ULL); //  1.05 MB [cast..GEMM2]

  // 0) weight casts
  cast_bf16_kernel<<<1024, 256, 0, stream>>>(in_proj_w, w1b, (2048 * 512) / 4);
  cast_bf16_kernel<<<512, 256, 0, stream>>>(out_proj_w, w2b, (512 * 1024) / 4);
  // 1) LayerNorm (bf16 out)
  ln_kernel<<<M_, 256, 0, stream>>>(x, norm_w, norm_b, xnb);
  // 2) xz = xn @ in_proj_w.T  (MFMA) -> split xpart | z (f32)
  gemm_bf16<0><<<dim3(2048 / 128, M_ / 128), 256, 0, stream>>>(
      xnb, w1b, M_, 2048, C_, xpart, z, nullptr);
  // 3) depthwise conv + SiLU
  conv_silu_kernel<<<M_, 256, 0, stream>>>(xpart, conv_w, conv_b, xc);
  // 4) x_dbl projections
  xdbl_kernel<<<B_ * K_ * 64, 256, 0, stream>>>(xc, x_proj_w, xdbl);
  // 5) chunked parallel selective scan (array-free register state)
  scan_passA<<<B_ * K_ * NC_ * 4, 256, 0, stream>>>(
      xc, xdbl, dt_projs_w, dt_projs_b, A_logs, st);
  scan_mid<<<(B_ * K_ * DI_) / 256, 256, 0, stream>>>(st);
  scan_passB<<<B_ * K_ * NC_ * 4, 256, 0, stream>>>(
      xc, xdbl, dt_projs_w, dt_projs_b, A_logs, Ds, st, ys);
  // 6) merge + out-LN + SiLU(z) gate (bf16 out)
  merge_kernel<<<M_, 256, 0, stream>>>(ys, z, out_norm_w, out_norm_b, ymb);
  // 7) out = ym @ out_proj_w.T + resid (MFMA)
  gemm_bf16<1><<<dim3(C_ / 128, M_ / 128), 256, 0, stream>>>(
      ymb, w2b, M_, C_, DI_, out, nullptr, x);
}